// Round 1
// baseline (234.945 us; speedup 1.0000x reference)
//
#include <hip/hip_runtime.h>
#include <stdint.h>

// Problem constants (B,T,J,D) = (64, 2048, 128, 256)
#define Bb 64
#define Tt 2048
#define Jj 128
#define Dd 256

// R6 structure (R5 + occupancy fix):
//  - sim_main: stage ALL 9 Up' tiles to LDS (72 KB) -- tile 8 (w1 column) was
//    register-resident (32 VGPRs) in R5, pushing live regs to ~146 -> at
//    >128 VGPR only ONE 512-thr block/CU fits (2 waves/SIMD). Moving it to
//    LDS + depth-3 H prefetch drops live to ~110, and __launch_bounds__(512,4)
//    pins <=128 VGPR -> 2 blocks/CU (4 waves/SIMD), doubling latency hiding
//    for the HBM-bound H stream and output stores.
//  - pack8 via (__bf16) casts -> compiler emits v_cvt_pk_bf16_f32 (same RNE
//    rounding as the manual sequence; m240: scalar casts are the fast path).
//  - prep_all unchanged (it already writes all 9 tiles).

typedef __attribute__((ext_vector_type(8))) __bf16 bf16x8;
typedef __attribute__((ext_vector_type(8))) unsigned short ushort8v;
typedef __attribute__((ext_vector_type(4))) float f32x4;

__device__ __forceinline__ unsigned short f2bf(float f) {
    unsigned int u = __builtin_bit_cast(unsigned int, f);
    u += 0x7FFFu + ((u >> 16) & 1u);
    return (unsigned short)(u >> 16);
}

__device__ __forceinline__ bf16x8 pack8(const float4& a0, const float4& a1) {
    bf16x8 r;
    r[0] = (__bf16)a0.x; r[1] = (__bf16)a0.y; r[2] = (__bf16)a0.z; r[3] = (__bf16)a0.w;
    r[4] = (__bf16)a1.x; r[5] = (__bf16)a1.y; r[6] = (__bf16)a1.z; r[7] = (__bf16)a1.w;
    return r;
}

// ---- fused prep: blocks 0..1151 build Up' (+w1 tile); 1152..3199 build s_u --
// Up' unit index ((b*9 + j)*8 + ks)*64 + l ; each unit = 16 B (8 bf16)
__global__ __launch_bounds__(256)
void prep_all(const float* __restrict__ U, const float* __restrict__ w,
              unsigned short* __restrict__ Up, float* __restrict__ su) {
    const int bid = blockIdx.x;
    const int tid = threadIdx.x;
    if (bid < 1152) {
        const int idx = bid * 256 + tid;               // 64*9*512 = 294912
        const int b   = idx / 4608;
        const int rem = idx - b * 4608;
        const int j   = rem >> 9;          // 0..8
        const int ks  = (rem >> 6) & 7;
        const int l   = idx & 63;
        const int k0  = ks * 32 + (l >> 4) * 8;

        ushort8v s;
        if (j < 8) {
            const int row = j * 16 + (l & 15);
            const float* up = U + ((size_t)(b * Jj + row)) * Dd + k0;
            const float* wp = w + 2 * Dd + k0;
            const float4 u0 = *(const float4*)(up);
            const float4 u1 = *(const float4*)(up + 4);
            const float4 w0 = *(const float4*)(wp);
            const float4 w1 = *(const float4*)(wp + 4);
            s[0] = f2bf(u0.x * w0.x); s[1] = f2bf(u0.y * w0.y);
            s[2] = f2bf(u0.z * w0.z); s[3] = f2bf(u0.w * w0.w);
            s[4] = f2bf(u1.x * w1.x); s[5] = f2bf(u1.y * w1.y);
            s[6] = f2bf(u1.z * w1.z); s[7] = f2bf(u1.w * w1.w);
        } else {
            // w1-column tile: B[n][k] = (n==0) ? w1[k] : 0
            const bool n0 = (l & 15) == 0;
#pragma unroll
            for (int e = 0; e < 8; ++e)
                s[e] = n0 ? f2bf(w[k0 + e]) : (unsigned short)0;
        }
        ((ushort8v*)Up)[idx] = s;
    } else {
        // s_u[row] = U[row][:] . w2, one wave per row
        const int row  = (bid - 1152) * 4 + (tid >> 6);    // 8192 rows
        const int lane = tid & 63;
        const float4 u = *(const float4*)(U + (size_t)row * Dd + lane * 4);
        const float4 v = *(const float4*)(w + Dd + lane * 4);
        float s = u.x * v.x + u.y * v.y + u.z * v.z + u.w * v.w;
#pragma unroll
        for (int d = 1; d < 64; d <<= 1) s += __shfl_xor(s, d);
        if (lane == 0) su[row] = s;
    }
}

// ---- main -------------------------------------------------------------------
__global__ __launch_bounds__(512, 4)
void sim_main(const float* __restrict__ H, const unsigned short* __restrict__ Up,
              const float* __restrict__ su, float* __restrict__ out) {
    __shared__ ushort8v lUp[4608];   // 72 KB: tiles j=0..8, unit (j*8+ks)*64+lane

    const int tid   = threadIdx.x;
    const int wid   = tid >> 6;
    const int lane  = tid & 63;
    const int row16 = lane & 15;
    const int quad  = lane >> 4;

    const int b  = blockIdx.x >> 4;                      // 16 blocks per batch
    const int m0 = (blockIdx.x & 15) * 128 + wid * 16;   // this wave's 16 rows

    // stage ALL 9 Up' tiles for this batch into LDS (coalesced 16B/thread)
    const ushort8v* Ub = (const ushort8v*)Up + (size_t)b * 9 * 512;
#pragma unroll
    for (int p = 0; p < 9; ++p)
        lUp[tid + p * 512] = Ub[tid + p * 512];

    // rolling depth-3 H prefetch (A-fragment layout: lane holds row m0+row16,
    // k-octet quad*8, slices of 32 along k)
    const float* Hp = H + ((size_t)(b * Tt + m0 + row16)) * Dd + quad * 8;
    float4 hb0[3], hb1[3];
#pragma unroll
    for (int p = 0; p < 3; ++p) {
        hb0[p] = *(const float4*)(Hp + p * 32);
        hb1[p] = *(const float4*)(Hp + p * 32 + 4);
    }

    f32x4 acc[9];
#pragma unroll
    for (int j = 0; j < 9; ++j) acc[j] = (f32x4){0.f, 0.f, 0.f, 0.f};

    __syncthreads();

#pragma unroll
    for (int ks = 0; ks < 8; ++ks) {
        const int slot = ks % 3;           // static under full unroll
        const float4 h0 = hb0[slot];
        const float4 h1 = hb1[slot];
        if (ks < 5) {                      // static: refill the slot
            hb0[slot] = *(const float4*)(Hp + (ks + 3) * 32);
            hb1[slot] = *(const float4*)(Hp + (ks + 3) * 32 + 4);
        }

        const bf16x8 af = pack8(h0, h1);
#pragma unroll
        for (int j = 0; j < 9; ++j) {
            const bf16x8 bf = __builtin_bit_cast(bf16x8, lUp[(j * 8 + ks) * 64 + lane]);
            acc[j] = __builtin_amdgcn_mfma_f32_16x16x32_bf16(af, bf, acc[j], 0, 0, 0);
        }
    }

    // s_h for output row quad*4+rg lives in lane quad*16 (col 0) of acc[8]
    float shv[4];
#pragma unroll
    for (int rg = 0; rg < 4; ++rg)
        shv[rg] = __shfl(acc[8][rg], quad * 16);

    // epilogue: C/D layout col = lane&15, row = quad*4 + reg (verified R1-R5)
    float* outW = out + ((size_t)(b * Tt + m0)) * Jj;
    const float* sub = su + b * Jj;
#pragma unroll
    for (int j = 0; j < 8; ++j) {
        const int col = j * 16 + row16;
        const float suv = sub[col];
#pragma unroll
        for (int rg = 0; rg < 4; ++rg)
            outW[(size_t)(quad * 4 + rg) * Jj + col] = acc[j][rg] + shv[rg] + suv;
    }
}

extern "C" void kernel_launch(void* const* d_in, const int* in_sizes, int n_in,
                              void* d_out, int out_size, void* d_ws, size_t ws_size,
                              hipStream_t stream) {
    const float* H = (const float*)d_in[0];
    const float* U = (const float*)d_in[1];
    const float* w = (const float*)d_in[2];
    float* out = (float*)d_out;

    unsigned short* Up = (unsigned short*)d_ws;            // 64*9*512*16 B = 4718592
    float* su = (float*)((char*)d_ws + (size_t)Bb * 9 * 512 * 16); // + 32 KB

    prep_all<<<3200, 256, 0, stream>>>(U, w, Up, su);
    sim_main<<<Bb * 16, 512, 0, stream>>>(H, Up, su, out);
}